// Round 1
// baseline (763.079 us; speedup 1.0000x reference)
//
#include <hip/hip_runtime.h>
#include <cstddef>

#define BATCH 16
#define NAGENT 1024
#define NNBR 1023
#define TSTEP 20
#define DIM 256
#define NEG_SLOPE 0.2f
#define TH2 2500.0f

// workspace layout (floats)
#define O_X   0                    // B*N*5 = 81920
#define O_H   81920                // B*N*256 = 4194304
#define O_AS  (81920+4194304)      // B*N*4 = 65536
#define O_AD  (O_AS+65536)
// total 4407296 floats = 17.6 MB  (wh lives in d_out's h region)

// ---------------------------------------------------------------- build x
__global__ void build_x(const float* __restrict__ ego,
                        const float* __restrict__ nbr,
                        float* __restrict__ x) {
    int tid = blockIdx.x * 256 + threadIdx.x;
    if (tid >= BATCH * NAGENT) return;
    int b = tid >> 10, n = tid & 1023;
    const float* src;
    if (n == 0) src = ego + (size_t)b * TSTEP * 7 + (TSTEP - 1) * 7;
    else        src = nbr + (((size_t)b * NNBR + (n - 1)) * TSTEP + (TSTEP - 1)) * 11;
    float* dst = x + (size_t)tid * 5;
#pragma unroll
    for (int k = 0; k < 5; k++) dst[k] = src[k];
}

// ---------------------------------------------------------------- node embed
__global__ __launch_bounds__(256) void node_embed(
    const float* __restrict__ x,
    const float* __restrict__ node_w, const float* __restrict__ node_b,
    const float* __restrict__ node_g, const float* __restrict__ node_beta,
    const float* __restrict__ ego_w, const float* __restrict__ ego_b,
    const float* __restrict__ ego_g, const float* __restrict__ ego_beta,
    float* __restrict__ h) {
    int row = blockIdx.x;
    int n = row & 1023;
    int t = threadIdx.x;
    __shared__ float sf[5];
    __shared__ float red[2][4];
    if (t < 5) sf[t] = x[(size_t)row * 5 + t];
    __syncthreads();
    const float *W, *bias, *g, *beta;
    if (n == 0) { W = ego_w;  bias = ego_b;  g = ego_g;  beta = ego_beta; }
    else        { W = node_w; bias = node_b; g = node_g; beta = node_beta; }
    float acc = bias[t];
#pragma unroll
    for (int k = 0; k < 5; k++) acc = fmaf(sf[k], W[k * DIM + t], acc);
    acc = fmaxf(acc, 0.f);
    float s1 = acc, s2 = acc * acc;
#pragma unroll
    for (int off = 32; off > 0; off >>= 1) {
        s1 += __shfl_down(s1, off);
        s2 += __shfl_down(s2, off);
    }
    int wave = t >> 6, lane = t & 63;
    if (lane == 0) { red[0][wave] = s1; red[1][wave] = s2; }
    __syncthreads();
    s1 = red[0][0] + red[0][1] + red[0][2] + red[0][3];
    s2 = red[1][0] + red[1][1] + red[1][2] + red[1][3];
    float mean = s1 * (1.f / 256.f);
    float var  = s2 * (1.f / 256.f) - mean * mean;
    float rstd = rsqrtf(var + 1e-5f);
    h[(size_t)row * DIM + t] = (acc - mean) * rstd * g[t] + beta[t];
}

// ---------------------------------------------------------------- GEMM: C[16384,256] = A @ W (+bias), optional a_s/a_d epilogue
__global__ __launch_bounds__(256) void gemm16(
    const float* __restrict__ A, const float* __restrict__ W,
    float* __restrict__ Cout, const float* __restrict__ bias,
    const float* __restrict__ asrc, const float* __restrict__ adst,
    float* __restrict__ a_s, float* __restrict__ a_d, int edge) {
    __shared__ float As[16 * DIM];
    int t = threadIdx.x;
    int row0 = blockIdx.x * 16;
    const float4* Ag4 = (const float4*)(A + (size_t)row0 * DIM);
    float4* As4 = (float4*)As;
#pragma unroll
    for (int k = 0; k < 4; k++) As4[t + k * 256] = Ag4[t + k * 256];
    __syncthreads();
    float acc[16];
#pragma unroll
    for (int r = 0; r < 16; r++) acc[r] = 0.f;
    for (int kk = 0; kk < 64; kk++) {
        float w0 = W[(4 * kk + 0) * DIM + t];
        float w1 = W[(4 * kk + 1) * DIM + t];
        float w2 = W[(4 * kk + 2) * DIM + t];
        float w3 = W[(4 * kk + 3) * DIM + t];
#pragma unroll
        for (int r = 0; r < 16; r++) {
            float4 av = As4[r * 64 + kk];
            acc[r] = fmaf(av.x, w0, acc[r]);
            acc[r] = fmaf(av.y, w1, acc[r]);
            acc[r] = fmaf(av.z, w2, acc[r]);
            acc[r] = fmaf(av.w, w3, acc[r]);
        }
    }
    if (bias) {
        float bv = bias[t];
#pragma unroll
        for (int r = 0; r < 16; r++) acc[r] += bv;
    }
#pragma unroll
    for (int r = 0; r < 16; r++) Cout[(size_t)(row0 + r) * DIM + t] = acc[r];
    if (edge) {
        int wave = t >> 6, lane = t & 63;
        float av = asrc[t], dv = adst[t];   // asrc[h*64+c] with h=t>>6,c=t&63 == asrc[t]
        for (int r = 0; r < 16; r++) {
            float ps = acc[r] * av, pd = acc[r] * dv;
#pragma unroll
            for (int off = 32; off > 0; off >>= 1) {
                ps += __shfl_down(ps, off);
                pd += __shfl_down(pd, off);
            }
            if (lane == 0) {
                a_s[(size_t)(row0 + r) * 4 + wave] = ps;
                a_d[(size_t)(row0 + r) * 4 + wave] = pd;
            }
        }
    }
}

// ---------------------------------------------------------------- fused GAT attention (softmax over j + aggregate + bias + relu)
__global__ __launch_bounds__(256) void gat_attn(
    const float* __restrict__ wh, const float* __restrict__ a_s,
    const float* __restrict__ a_d, const float* __restrict__ x,
    const float* __restrict__ gat_b, float* __restrict__ hout) {
    int t = threadIdx.x;
    int blk = blockIdx.x;
    int b = blk >> 6;
    int i0 = (blk & 63) << 4;       // 16 rows per block
    int base = b * NAGENT;

    __shared__ float pos_i[16][2];
    __shared__ float adi[16][4];          // [i][h]
    __shared__ float m_sh[64];            // [h*16+i]
    __shared__ float s_sh[64];
    __shared__ float red[4][64];
    __shared__ float asj1[256 * 4];       // pass-1 a_s chunk  [j][h]
    __shared__ float posj1[256][2];
    __shared__ float whs[32 * DIM];       // pass-2 wh chunk (32 rows)
    __shared__ float p_lds[32 * 64];      // p: [j][h][i]
    __shared__ float asj2[32 * 4];
    __shared__ float posj2[32][2];

    if (t < 32) pos_i[t >> 1][t & 1] = x[(size_t)(base + i0 + (t >> 1)) * 5 + (t & 1)];
    if (t < 64) adi[t >> 2][t & 3]   = a_d[(size_t)(base + i0 + (t >> 2)) * 4 + (t & 3)];
    __syncthreads();

    int il = t & 15, hh = (t >> 4) & 3, slice = t >> 6;
    float xi = pos_i[il][0], yi = pos_i[il][1];
    float adv = adi[il][hh];

    // ---- pass 1: row max over all j
    float lmax = -3e38f;
    for (int c = 0; c < 4; c++) {
        int j0 = c * 256;
        ((float4*)asj1)[t] = ((const float4*)(a_s + (size_t)(base + j0) * 4))[t];
        posj1[t][0] = x[(size_t)(base + j0 + t) * 5 + 0];
        posj1[t][1] = x[(size_t)(base + j0 + t) * 5 + 1];
        __syncthreads();
        for (int k = 0; k < 64; k++) {
            int j = slice + (k << 2);
            float dx = posj1[j][0] - xi, dy = posj1[j][1] - yi;
            float d2 = dx * dx + dy * dy;
            bool adj = (d2 < TH2) || (j0 + j == i0 + il);
            float sc = asj1[j * 4 + hh] + adv;
            sc = sc > 0.f ? sc : NEG_SLOPE * sc;
            sc = adj ? sc : -1e9f;
            lmax = fmaxf(lmax, sc);
        }
        __syncthreads();
    }
    red[slice][hh * 16 + il] = lmax;
    __syncthreads();
    if (t < 64) {
        float m = fmaxf(fmaxf(red[0][t], red[1][t]), fmaxf(red[2][t], red[3][t]));
        m_sh[t] = m;
    }
    __syncthreads();
    float mA = m_sh[hh * 16 + il];

    // ---- pass 2: p + aggregate
    float acc[4][4];
#pragma unroll
    for (int a = 0; a < 4; a++)
#pragma unroll
        for (int c2 = 0; c2 < 4; c2++) acc[a][c2] = 0.f;
    float s_loc = 0.f;

    int hb = t >> 6, q = t & 15, r4 = (t >> 4) & 3;

    for (int c = 0; c < 32; c++) {
        int j0 = c * 32;
        const float4* wg4 = (const float4*)(wh + (size_t)(base + j0) * DIM);
        float4* ws4 = (float4*)whs;
#pragma unroll
        for (int k = 0; k < 8; k++) ws4[t + k * 256] = wg4[t + k * 256];
        if (t < 128) asj2[t] = a_s[(size_t)(base + j0) * 4 + t];
        if (t < 64)  posj2[t >> 1][t & 1] = x[(size_t)(base + j0 + (t >> 1)) * 5 + (t & 1)];
        __syncthreads();
        // phase A: p[j][h][i]
#pragma unroll
        for (int k = 0; k < 8; k++) {
            int j = slice + (k << 2);
            float dx = posj2[j][0] - xi, dy = posj2[j][1] - yi;
            float d2 = dx * dx + dy * dy;
            bool adj = (d2 < TH2) || (j0 + j == i0 + il);
            float sc = asj2[j * 4 + hh] + adv;
            sc = sc > 0.f ? sc : NEG_SLOPE * sc;
            float p = adj ? __expf(sc - mA) : 0.f;
            p_lds[j * 64 + hh * 16 + il] = p;
        }
        __syncthreads();
        // phase B: acc[ri][ci] += p[r4*4+ri][j][hb] * wh[j][hb*64+q*4+ci]
        const float4* p4 = (const float4*)p_lds;
        const float4* w4 = (const float4*)whs;
#pragma unroll 8
        for (int j = 0; j < 32; j++) {
            float4 pv = p4[j * 16 + hb * 4 + r4];
            float4 wv = w4[j * 64 + hb * 16 + q];
            acc[0][0] = fmaf(pv.x, wv.x, acc[0][0]);
            acc[0][1] = fmaf(pv.x, wv.y, acc[0][1]);
            acc[0][2] = fmaf(pv.x, wv.z, acc[0][2]);
            acc[0][3] = fmaf(pv.x, wv.w, acc[0][3]);
            acc[1][0] = fmaf(pv.y, wv.x, acc[1][0]);
            acc[1][1] = fmaf(pv.y, wv.y, acc[1][1]);
            acc[1][2] = fmaf(pv.y, wv.z, acc[1][2]);
            acc[1][3] = fmaf(pv.y, wv.w, acc[1][3]);
            acc[2][0] = fmaf(pv.z, wv.x, acc[2][0]);
            acc[2][1] = fmaf(pv.z, wv.y, acc[2][1]);
            acc[2][2] = fmaf(pv.z, wv.z, acc[2][2]);
            acc[2][3] = fmaf(pv.z, wv.w, acc[2][3]);
            acc[3][0] = fmaf(pv.w, wv.x, acc[3][0]);
            acc[3][1] = fmaf(pv.w, wv.y, acc[3][1]);
            acc[3][2] = fmaf(pv.w, wv.z, acc[3][2]);
            acc[3][3] = fmaf(pv.w, wv.w, acc[3][3]);
        }
        if (t < 64) {
            int is = t & 15, hs = (t >> 4) & 3;
#pragma unroll
            for (int j = 0; j < 32; j++) s_loc += p_lds[j * 64 + hs * 16 + is];
        }
        __syncthreads();
    }
    if (t < 64) s_sh[((t >> 4) & 3) * 16 + (t & 15)] = s_loc;
    __syncthreads();

    int c0 = hb * 64 + q * 4;
#pragma unroll
    for (int ri = 0; ri < 4; ri++) {
        int i = r4 * 4 + ri;
        float inv = 1.f / s_sh[hb * 16 + i];
        float4 o;
        o.x = fmaxf(fmaf(acc[ri][0], inv, 0.f) + gat_b[c0 + 0], 0.f);
        o.y = fmaxf(fmaf(acc[ri][1], inv, 0.f) + gat_b[c0 + 1], 0.f);
        o.z = fmaxf(fmaf(acc[ri][2], inv, 0.f) + gat_b[c0 + 2], 0.f);
        o.w = fmaxf(fmaf(acc[ri][3], inv, 0.f) + gat_b[c0 + 3], 0.f);
        *(float4*)(hout + (size_t)(base + i0 + i) * DIM + c0) = o;
    }
}

// ---------------------------------------------------------------- mask zeros
__global__ void zero_mask(float* __restrict__ p) {
    p[blockIdx.x * 256 + threadIdx.x] = 0.f;
}

// ---------------------------------------------------------------- launch
extern "C" void kernel_launch(void* const* d_in, const int* in_sizes, int n_in,
                              void* d_out, int out_size, void* d_ws, size_t ws_size,
                              hipStream_t stream) {
    const float* ego       = (const float*)d_in[0];
    const float* nbr       = (const float*)d_in[1];
    const float* node_w    = (const float*)d_in[2];
    const float* node_b    = (const float*)d_in[3];
    const float* node_g    = (const float*)d_in[4];
    const float* node_beta = (const float*)d_in[5];
    const float* ego_w     = (const float*)d_in[6];
    const float* ego_b     = (const float*)d_in[7];
    const float* ego_g     = (const float*)d_in[8];
    const float* ego_beta  = (const float*)d_in[9];
    const float* gat_w     = (const float*)d_in[10];
    const float* gat_asrc  = (const float*)d_in[11];
    const float* gat_adst  = (const float*)d_in[12];
    const float* gat_bias  = (const float*)d_in[13];
    const float* proj_w    = (const float*)d_in[14];
    const float* proj_b    = (const float*)d_in[15];

    float* out = (float*)d_out;
    float* ws  = (float*)d_ws;
    float* x   = ws + O_X;
    float* h   = ws + O_H;
    float* as_ = ws + O_AS;
    float* ad_ = ws + O_AD;
    float* wh  = out;   // reuse d_out h-region (16.8 MB) as wh scratch; proj overwrites it last

    build_x<<<64, 256, 0, stream>>>(ego, nbr, x);
    node_embed<<<BATCH * NAGENT, 256, 0, stream>>>(x, node_w, node_b, node_g, node_beta,
                                                   ego_w, ego_b, ego_g, ego_beta, h);
    for (int l = 0; l < 2; l++) {
        gemm16<<<1024, 256, 0, stream>>>(h, gat_w + l * 65536, wh, nullptr,
                                         gat_asrc + l * 256, gat_adst + l * 256,
                                         as_, ad_, 1);
        gat_attn<<<1024, 256, 0, stream>>>(wh, as_, ad_, x, gat_bias + l * 256, h);
    }
    gemm16<<<1024, 256, 0, stream>>>(h, proj_w, out, proj_b,
                                     nullptr, nullptr, nullptr, nullptr, 0);
    zero_mask<<<64, 256, 0, stream>>>(out + BATCH * NAGENT * DIM);
}

// Round 2
// 422.105 us; speedup vs baseline: 1.8078x; 1.8078x over previous
//
#include <hip/hip_runtime.h>
#include <cstddef>

typedef _Float16 f16;
typedef _Float16 f16x8 __attribute__((ext_vector_type(8)));
typedef float f32x4 __attribute__((ext_vector_type(4)));

#define BATCH 16
#define NAGENT 1024
#define NNBR 1023
#define TSTEP 20
#define DIM 256
#define ROWS 16384            // BATCH*NAGENT
#define TH2 2500.0f

// workspace layout (float offsets)
#define O_X   0               // B*N*5
#define O_H   81920           // B*N*256
#define O_AS  4276224         // [4][16384]  a_s transposed (head-major)
#define O_AD  4341760         // [4][16384]
#define O_PX  4407296         // [16384] pos x
#define O_PY  4423680         // [16384] pos y
#define O_M   4440064         // [64]  per (b,h) score max
// total 4440128 floats = 17.76 MB

// ---------------------------------------------------------------- build x (+pos arrays)
__global__ void build_x(const float* __restrict__ ego,
                        const float* __restrict__ nbr,
                        float* __restrict__ x,
                        float* __restrict__ posx,
                        float* __restrict__ posy) {
    int tid = blockIdx.x * 256 + threadIdx.x;
    if (tid >= ROWS) return;
    int b = tid >> 10, n = tid & 1023;
    const float* src;
    if (n == 0) src = ego + (size_t)b * TSTEP * 7 + (TSTEP - 1) * 7;
    else        src = nbr + (((size_t)b * NNBR + (n - 1)) * TSTEP + (TSTEP - 1)) * 11;
    float* dst = x + (size_t)tid * 5;
#pragma unroll
    for (int k = 0; k < 5; k++) dst[k] = src[k];
    posx[tid] = src[0];
    posy[tid] = src[1];
}

// ---------------------------------------------------------------- node embed (relu + LN)
__global__ __launch_bounds__(256) void node_embed(
    const float* __restrict__ x,
    const float* __restrict__ node_w, const float* __restrict__ node_b,
    const float* __restrict__ node_g, const float* __restrict__ node_beta,
    const float* __restrict__ ego_w, const float* __restrict__ ego_b,
    const float* __restrict__ ego_g, const float* __restrict__ ego_beta,
    float* __restrict__ h) {
    int row = blockIdx.x;
    int n = row & 1023;
    int t = threadIdx.x;
    __shared__ float sf[5];
    __shared__ float red[2][4];
    if (t < 5) sf[t] = x[(size_t)row * 5 + t];
    __syncthreads();
    const float *W, *bias, *g, *beta;
    if (n == 0) { W = ego_w;  bias = ego_b;  g = ego_g;  beta = ego_beta; }
    else        { W = node_w; bias = node_b; g = node_g; beta = node_beta; }
    float acc = bias[t];
#pragma unroll
    for (int k = 0; k < 5; k++) acc = fmaf(sf[k], W[k * DIM + t], acc);
    acc = fmaxf(acc, 0.f);
    float s1 = acc, s2 = acc * acc;
#pragma unroll
    for (int off = 32; off > 0; off >>= 1) {
        s1 += __shfl_down(s1, off);
        s2 += __shfl_down(s2, off);
    }
    int wave = t >> 6, lane = t & 63;
    if (lane == 0) { red[0][wave] = s1; red[1][wave] = s2; }
    __syncthreads();
    s1 = red[0][0] + red[0][1] + red[0][2] + red[0][3];
    s2 = red[1][0] + red[1][1] + red[1][2] + red[1][3];
    float mean = s1 * (1.f / 256.f);
    float var  = s2 * (1.f / 256.f) - mean * mean;
    float rstd = rsqrtf(var + 1e-5f);
    h[(size_t)row * DIM + t] = (acc - mean) * rstd * g[t] + beta[t];
}

// ---------------------------------------------------------------- GEMM: [16384,256] @ [256,256]
// edge: emit whT (f16, K-contiguous [256][16384]) + a_sT/a_dT [4][16384]
// else: emit fp32 Cout (+bias)
__global__ __launch_bounds__(256) void gemm16(
    const float* __restrict__ A, const float* __restrict__ W,
    float* __restrict__ Cout, const float* __restrict__ bias,
    const float* __restrict__ asrc, const float* __restrict__ adst,
    float* __restrict__ a_sT, float* __restrict__ a_dT,
    f16* __restrict__ whT, int edge) {
    __shared__ float As[16 * DIM];
    int t = threadIdx.x;
    int row0 = blockIdx.x * 16;
    const float4* Ag4 = (const float4*)(A + (size_t)row0 * DIM);
    float4* As4 = (float4*)As;
#pragma unroll
    for (int k = 0; k < 4; k++) As4[t + k * 256] = Ag4[t + k * 256];
    __syncthreads();
    float acc[16];
#pragma unroll
    for (int r = 0; r < 16; r++) acc[r] = 0.f;
    for (int kk = 0; kk < 64; kk++) {
        float w0 = W[(4 * kk + 0) * DIM + t];
        float w1 = W[(4 * kk + 1) * DIM + t];
        float w2 = W[(4 * kk + 2) * DIM + t];
        float w3 = W[(4 * kk + 3) * DIM + t];
#pragma unroll
        for (int r = 0; r < 16; r++) {
            float4 av = As4[r * 64 + kk];
            acc[r] = fmaf(av.x, w0, acc[r]);
            acc[r] = fmaf(av.y, w1, acc[r]);
            acc[r] = fmaf(av.z, w2, acc[r]);
            acc[r] = fmaf(av.w, w3, acc[r]);
        }
    }
    if (!edge) {
        float bv = bias ? bias[t] : 0.f;
#pragma unroll
        for (int r = 0; r < 16; r++)
            Cout[(size_t)(row0 + r) * DIM + t] = acc[r] + bv;
        return;
    }
    // ---- edge epilogue: whT f16 (transposed, K-contiguous), a_sT/a_dT
    f16x8 p0, p1;
#pragma unroll
    for (int r = 0; r < 8; r++) { p0[r] = (f16)acc[r]; p1[r] = (f16)acc[r + 8]; }
    f16* wd = whT + (size_t)t * ROWS + row0;
    *(f16x8*)wd = p0;
    *((f16x8*)wd + 1) = p1;

    int wave = t >> 6, lane = t & 63;
    float av = asrc[t], dv = adst[t];   // asrc[h*64+c], h=t>>6, c=t&63
    for (int r = 0; r < 16; r++) {
        float ps = acc[r] * av, pd = acc[r] * dv;
#pragma unroll
        for (int off = 32; off > 0; off >>= 1) {
            ps += __shfl_down(ps, off);
            pd += __shfl_down(pd, off);
        }
        if (lane == 0) {
            a_sT[(size_t)wave * ROWS + row0 + r] = ps;
            a_dT[(size_t)wave * ROWS + row0 + r] = pd;
        }
    }
}

// ---------------------------------------------------------------- per (b,h) max of a_s over all j
__global__ __launch_bounds__(256) void reduce_max(const float* __restrict__ a_sT,
                                                  float* __restrict__ M) {
    int blk = blockIdx.x;           // b*4 + h
    int b = blk >> 2, h = blk & 3;
    const float* p = a_sT + (size_t)h * ROWS + b * NAGENT;
    int t = threadIdx.x;
    float m = fmaxf(fmaxf(p[t], p[t + 256]), fmaxf(p[t + 512], p[t + 768]));
#pragma unroll
    for (int off = 32; off > 0; off >>= 1) m = fmaxf(m, __shfl_down(m, off));
    __shared__ float red[4];
    if ((t & 63) == 0) red[t >> 6] = m;
    __syncthreads();
    if (t == 0) M[blk] = fmaxf(fmaxf(red[0], red[1]), fmaxf(red[2], red[3]));
}

// ---------------------------------------------------------------- fused GAT attention, f16 MFMA
// block = 256 thr = 4 waves; wave = head. 16 i-rows per block, K-loop over 1024 j.
__global__ __launch_bounds__(256, 4) void gat_attn(
    const f16* __restrict__ whT, const float* __restrict__ a_sT,
    const float* __restrict__ a_dT, const float* __restrict__ posx,
    const float* __restrict__ posy, const float* __restrict__ M,
    const float* __restrict__ gat_b, float* __restrict__ hout) {
    int t = threadIdx.x;
    int blk = blockIdx.x;
    int b = blk >> 6;
    int i0 = (blk & 63) << 4;
    int base = b * NAGENT;
    int h = t >> 6, lane = t & 63;
    int il = lane & 15, q = lane >> 4;
    int ig = i0 + il;

    float adv = a_dT[(size_t)h * ROWS + base + ig];
    float mz = M[b * 4 + h] + adv;
    float m_i = fmaxf(mz, 0.2f * mz);          // leaky(maxj a_s + a_d_i): exact row-max bound
    float xi = posx[base + ig], yi = posy[base + ig];

    f32x4 acc0 = {0.f, 0.f, 0.f, 0.f}, acc1 = acc0, acc2 = acc0, acc3 = acc0;
    float s_acc = 0.f;

    const f16*   wp  = whT + (size_t)(h * 64 + il) * ROWS + base + q * 8;
    const float* asp = a_sT + (size_t)h * ROWS + base + q * 8;
    const float* pxp = posx + base + q * 8;
    const float* pyp = posy + base + q * 8;

    for (int c = 0; c < 32; ++c) {
        int j0 = c * 32;
        // B-frags: WH[k=q*8+jj][n=il] for 4 c-tiles (K-contiguous f16 -> 1 dwordx4 each)
        f16x8 b0 = *(const f16x8*)(wp + j0);
        f16x8 b1 = *(const f16x8*)(wp + (size_t)16 * ROWS + j0);
        f16x8 b2 = *(const f16x8*)(wp + (size_t)32 * ROWS + j0);
        f16x8 b3 = *(const f16x8*)(wp + (size_t)48 * ROWS + j0);
        float4 as0 = *(const float4*)(asp + j0);
        float4 as1 = *(const float4*)(asp + j0 + 4);
        float4 px0 = *(const float4*)(pxp + j0);
        float4 px1 = *(const float4*)(pxp + j0 + 4);
        float4 py0 = *(const float4*)(pyp + j0);
        float4 py1 = *(const float4*)(pyp + j0 + 4);
        float asv[8] = {as0.x, as0.y, as0.z, as0.w, as1.x, as1.y, as1.z, as1.w};
        float pxv[8] = {px0.x, px0.y, px0.z, px0.w, px1.x, px1.y, px1.z, px1.w};
        float pyv[8] = {py0.x, py0.y, py0.z, py0.w, py1.x, py1.y, py1.z, py1.w};
        // A-frag: P[m=il][k=q*8+jj], computed in-register
        f16x8 afr;
#pragma unroll
        for (int jj = 0; jj < 8; ++jj) {
            float dx = pxv[jj] - xi, dy = pyv[jj] - yi;
            float d2 = dx * dx + dy * dy;
            int jg = j0 + q * 8 + jj;
            bool adj = (d2 < TH2) || (jg == ig);
            float z = asv[jj] + adv;
            float sc = fmaxf(z, 0.2f * z);     // leaky_relu
            float p = adj ? __expf(sc - m_i) : 0.f;
            s_acc += p;
            afr[jj] = (f16)p;
        }
        acc0 = __builtin_amdgcn_mfma_f32_16x16x32_f16(afr, b0, acc0, 0, 0, 0);
        acc1 = __builtin_amdgcn_mfma_f32_16x16x32_f16(afr, b1, acc1, 0, 0, 0);
        acc2 = __builtin_amdgcn_mfma_f32_16x16x32_f16(afr, b2, acc2, 0, 0, 0);
        acc3 = __builtin_amdgcn_mfma_f32_16x16x32_f16(afr, b3, acc3, 0, 0, 0);
    }
    // denominator: reduce over the 4 q-octets holding the same i
    s_acc += __shfl_xor(s_acc, 16);
    s_acc += __shfl_xor(s_acc, 32);
    __shared__ float s_sh[4][16];
    if (q == 0) s_sh[h][il] = 1.f / s_acc;
    __syncthreads();
    float4 sv = *(const float4*)&s_sh[h][q * 4];   // 1/s for rows q*4+0..3
    float sva[4] = {sv.x, sv.y, sv.z, sv.w};
    float b0v = gat_b[h * 64 + il];
    float b1v = gat_b[h * 64 + 16 + il];
    float b2v = gat_b[h * 64 + 32 + il];
    float b3v = gat_b[h * 64 + 48 + il];
    // C/D: col = lane&15 (= channel il), row = q*4 + reg (= i)
#pragma unroll
    for (int reg = 0; reg < 4; ++reg) {
        size_t ro = (size_t)(base + i0 + q * 4 + reg) * DIM + h * 64 + il;
        hout[ro +  0] = fmaxf(acc0[reg] * sva[reg] + b0v, 0.f);
        hout[ro + 16] = fmaxf(acc1[reg] * sva[reg] + b1v, 0.f);
        hout[ro + 32] = fmaxf(acc2[reg] * sva[reg] + b2v, 0.f);
        hout[ro + 48] = fmaxf(acc3[reg] * sva[reg] + b3v, 0.f);
    }
}

// ---------------------------------------------------------------- mask zeros
__global__ void zero_mask(float* __restrict__ p) {
    p[blockIdx.x * 256 + threadIdx.x] = 0.f;
}

// ---------------------------------------------------------------- launch
extern "C" void kernel_launch(void* const* d_in, const int* in_sizes, int n_in,
                              void* d_out, int out_size, void* d_ws, size_t ws_size,
                              hipStream_t stream) {
    const float* ego       = (const float*)d_in[0];
    const float* nbr       = (const float*)d_in[1];
    const float* node_w    = (const float*)d_in[2];
    const float* node_b    = (const float*)d_in[3];
    const float* node_g    = (const float*)d_in[4];
    const float* node_beta = (const float*)d_in[5];
    const float* ego_w     = (const float*)d_in[6];
    const float* ego_b     = (const float*)d_in[7];
    const float* ego_g     = (const float*)d_in[8];
    const float* ego_beta  = (const float*)d_in[9];
    const float* gat_w     = (const float*)d_in[10];
    const float* gat_asrc  = (const float*)d_in[11];
    const float* gat_adst  = (const float*)d_in[12];
    const float* gat_bias  = (const float*)d_in[13];
    const float* proj_w    = (const float*)d_in[14];
    const float* proj_b    = (const float*)d_in[15];

    float* out = (float*)d_out;
    float* ws  = (float*)d_ws;
    float* x    = ws + O_X;
    float* h    = ws + O_H;
    float* asT  = ws + O_AS;
    float* adT  = ws + O_AD;
    float* px   = ws + O_PX;
    float* py   = ws + O_PY;
    float* Mmax = ws + O_M;
    f16*   whT  = (f16*)d_out;    // 8 MB scratch inside d_out; proj overwrites last

    build_x<<<64, 256, 0, stream>>>(ego, nbr, x, px, py);
    node_embed<<<ROWS, 256, 0, stream>>>(x, node_w, node_b, node_g, node_beta,
                                         ego_w, ego_b, ego_g, ego_beta, h);
    for (int l = 0; l < 2; l++) {
        gemm16<<<1024, 256, 0, stream>>>(h, gat_w + l * 65536, nullptr, nullptr,
                                         gat_asrc + l * 256, gat_adst + l * 256,
                                         asT, adT, whT, 1);
        reduce_max<<<64, 256, 0, stream>>>(asT, Mmax);
        gat_attn<<<1024, 256, 0, stream>>>(whT, asT, adT, px, py, Mmax,
                                           gat_bias + l * 256, h);
    }
    gemm16<<<1024, 256, 0, stream>>>(h, proj_w, out, proj_b,
                                     nullptr, nullptr, nullptr, nullptr, nullptr, 0);
    zero_mask<<<64, 256, 0, stream>>>(out + ROWS * DIM);
}

// Round 3
// 387.761 us; speedup vs baseline: 1.9679x; 1.0886x over previous
//
#include <hip/hip_runtime.h>
#include <cstddef>

typedef _Float16 f16;
typedef _Float16 f16x8 __attribute__((ext_vector_type(8)));
typedef _Float16 f16x4 __attribute__((ext_vector_type(4)));
typedef float f32x4 __attribute__((ext_vector_type(4)));

#define BATCH 16
#define NAGENT 1024
#define NNBR 1023
#define TSTEP 20
#define DIM 256
#define ROWS 16384
#define TH2 2500.0f
#define LOG2E 1.44269504089f

// ---- workspace layout (float offsets) ----
#define O_X    0           // [16384][5]
#define O_PX   81920       // [16384]
#define O_PY   98304       // [16384]
#define O_H16  114688      // f16 [16384][256]  (2097152 floats)
#define O_AS   2211840     // [4][16384]
#define O_AD   2277376     // [4][16384]
#define O_M    2342912     // [64]
#define O_US   2342976     // [2][4][256]
#define O_UD   2345024     // [2][4][256]
#define O_WT   2347072     // f16 [3][256][256] (98304 floats)
#define O_ADJ  2445376     // uint32 [16][1024][32] (524288 words)
// total 2969664 floats = 11.9 MB

// ---------------------------------------------------------------- build x + pos
__global__ void build_x(const float* __restrict__ ego,
                        const float* __restrict__ nbr,
                        float* __restrict__ x,
                        float* __restrict__ posx,
                        float* __restrict__ posy) {
    int tid = blockIdx.x * 256 + threadIdx.x;
    if (tid >= ROWS) return;
    int b = tid >> 10, n = tid & 1023;
    const float* src;
    if (n == 0) src = ego + (size_t)b * TSTEP * 7 + (TSTEP - 1) * 7;
    else        src = nbr + (((size_t)b * NNBR + (n - 1)) * TSTEP + (TSTEP - 1)) * 11;
    float* dst = x + (size_t)tid * 5;
#pragma unroll
    for (int k = 0; k < 5; k++) dst[k] = src[k];
    posx[tid] = src[0];
    posy[tid] = src[1];
}

// ---------------------------------------------------------------- adjacency bitmask (once, reused both layers)
__global__ __launch_bounds__(256) void adj_build(const float* __restrict__ px,
                                                 const float* __restrict__ py,
                                                 unsigned int* __restrict__ mask) {
    int blk = blockIdx.x;           // b*64 + ichunk
    int b = blk >> 6, ic = blk & 63;
    int base = b << 10;
    __shared__ float sx[1024], sy[1024];
    int t = threadIdx.x;
#pragma unroll
    for (int i = 0; i < 4; i++) {
        sx[t + i * 256] = px[base + t + i * 256];
        sy[t + i * 256] = py[base + t + i * 256];
    }
    __syncthreads();
    int i_loc = t >> 4;             // 0..15
    int wrd2 = t & 15;              // covers 64 j
    int ig = ic * 16 + i_loc;
    float xi = sx[ig], yi = sy[ig];
    unsigned int w0 = 0, w1 = 0;
    int j0 = wrd2 * 64;
#pragma unroll
    for (int jj = 0; jj < 32; jj++) {
        int j = j0 + jj;
        float dx = sx[j] - xi, dy = sy[j] - yi;
        if ((dx * dx + dy * dy < TH2) || (j == ig)) w0 |= 1u << jj;
        int j2 = j + 32;
        dx = sx[j2] - xi; dy = sy[j2] - yi;
        if ((dx * dx + dy * dy < TH2) || (j2 == ig)) w1 |= 1u << jj;
    }
    uint2 v; v.x = w0; v.y = w1;
    *(uint2*)(mask + (((size_t)(base + ig)) << 5) + wrd2 * 2) = v;
}

// ---------------------------------------------------------------- us/ud = W @ asrc/adst per (l,h)
__global__ void prep_usud(const float* __restrict__ gat_w,
                          const float* __restrict__ asrc,
                          const float* __restrict__ adst,
                          float* __restrict__ us, float* __restrict__ ud) {
    int blk = blockIdx.x;           // l*4 + h
    int l = blk >> 2, h = blk & 3;
    int k = threadIdx.x;
    const float* W  = gat_w + (size_t)l * 65536 + k * 256 + h * 64;
    const float* as = asrc + l * 256 + h * 64;
    const float* ad = adst + l * 256 + h * 64;
    float s = 0.f, d = 0.f;
#pragma unroll 8
    for (int c = 0; c < 64; c++) { s = fmaf(W[c], as[c], s); d = fmaf(W[c], ad[c], d); }
    us[blk * 256 + k] = s;
    ud[blk * 256 + k] = d;
}

// ---------------------------------------------------------------- W [k][n] fp32 -> WT f16 [n][k]
__global__ __launch_bounds__(256) void transpose_w(const float* __restrict__ gat_w,
                                                   const float* __restrict__ proj_w,
                                                   f16* __restrict__ WT) {
    int bid = blockIdx.x;           // 3 mats * 16 tiles
    int m = bid >> 4, t4 = bid & 15;
    int ti = (t4 >> 2) * 64;        // k base
    int tj = (t4 & 3) * 64;         // n base
    const float* W = (m < 2) ? (gat_w + (size_t)m * 65536) : proj_w;
    __shared__ float ls[64][68];
    int t = threadIdx.x;
#pragma unroll
    for (int i = 0; i < 4; i++) {
        int idx = t + i * 256;
        int r = idx >> 4, c4 = (idx & 15) * 4;
        float4 v = *(const float4*)(W + (size_t)(ti + r) * 256 + tj + c4);
        ls[r][c4] = v.x; ls[r][c4 + 1] = v.y; ls[r][c4 + 2] = v.z; ls[r][c4 + 3] = v.w;
    }
    __syncthreads();
#pragma unroll
    for (int i = 0; i < 2; i++) {
        int idx = t + i * 256;
        int nr = idx >> 3, kc = (idx & 7) * 8;
        f16x8 v;
#pragma unroll
        for (int j = 0; j < 8; j++) v[j] = (f16)ls[kc + j][nr];
        *(f16x8*)(WT + (size_t)m * 65536 + (size_t)(tj + nr) * 256 + ti + kc) = v;
    }
}

// ---------------------------------------------------------------- node embed: wave per row, shuffle-only LN, f16 out
__global__ __launch_bounds__(256) void node_embed(
    const float* __restrict__ x,
    const float* __restrict__ node_w, const float* __restrict__ node_b,
    const float* __restrict__ node_g, const float* __restrict__ node_beta,
    const float* __restrict__ ego_w, const float* __restrict__ ego_b,
    const float* __restrict__ ego_g, const float* __restrict__ ego_beta,
    f16* __restrict__ h16) {
    int w = threadIdx.x >> 6, lane = threadIdx.x & 63;
    int row = blockIdx.x * 4 + w;
    int n = row & 1023;
    const float *W, *bias, *g, *beta;
    if (n == 0) { W = ego_w;  bias = ego_b;  g = ego_g;  beta = ego_beta; }
    else        { W = node_w; bias = node_b; g = node_g; beta = node_beta; }
    float xv[5];
#pragma unroll
    for (int k = 0; k < 5; k++) xv[k] = x[(size_t)row * 5 + k];
    int c0 = lane * 4;
    float4 bv = *(const float4*)(bias + c0);
    float acc[4] = {bv.x, bv.y, bv.z, bv.w};
#pragma unroll
    for (int k = 0; k < 5; k++) {
        float4 wv = *(const float4*)(W + (size_t)k * 256 + c0);
        acc[0] = fmaf(xv[k], wv.x, acc[0]);
        acc[1] = fmaf(xv[k], wv.y, acc[1]);
        acc[2] = fmaf(xv[k], wv.z, acc[2]);
        acc[3] = fmaf(xv[k], wv.w, acc[3]);
    }
#pragma unroll
    for (int c = 0; c < 4; c++) acc[c] = fmaxf(acc[c], 0.f);
    float s1 = acc[0] + acc[1] + acc[2] + acc[3];
    float s2 = acc[0]*acc[0] + acc[1]*acc[1] + acc[2]*acc[2] + acc[3]*acc[3];
#pragma unroll
    for (int off = 1; off < 64; off <<= 1) {
        s1 += __shfl_xor(s1, off);
        s2 += __shfl_xor(s2, off);
    }
    float mean = s1 * (1.f / 256.f);
    float var  = s2 * (1.f / 256.f) - mean * mean;
    float rstd = rsqrtf(var + 1e-5f);
    float4 gv = *(const float4*)(g + c0);
    float4 be = *(const float4*)(beta + c0);
    f16x4 o;
    o[0] = (f16)((acc[0] - mean) * rstd * gv.x + be.x);
    o[1] = (f16)((acc[1] - mean) * rstd * gv.y + be.y);
    o[2] = (f16)((acc[2] - mean) * rstd * gv.z + be.z);
    o[3] = (f16)((acc[3] - mean) * rstd * gv.w + be.w);
    *(f16x4*)(h16 + (size_t)row * 256 + c0) = o;
}

// ---------------------------------------------------------------- f16 MFMA GEMM [16384,256] @ WT[256n][256k]
// edge mode: whT f16 [256][16384]; final mode: fp32 out + bias
__global__ __launch_bounds__(256, 4) void gemm_f16(
    const f16* __restrict__ A, const f16* __restrict__ BT,
    f16* __restrict__ whT, float* __restrict__ outF, const float* __restrict__ bias) {
    int t = threadIdx.x;
    int w = t >> 6, lane = t & 63;
    int il = lane & 15, q = lane >> 4;
    int m0 = blockIdx.x * 32;
    int n0 = w * 64;
    f32x4 acc[2][4];
#pragma unroll
    for (int mt = 0; mt < 2; mt++)
#pragma unroll
        for (int nt = 0; nt < 4; nt++) acc[mt][nt] = (f32x4){0.f, 0.f, 0.f, 0.f};
    const f16* Ap = A + (size_t)(m0 + il) * 256 + q * 8;
    const f16* Bp = BT + (size_t)(n0 + il) * 256 + q * 8;
#pragma unroll 2
    for (int ks = 0; ks < 256; ks += 32) {
        f16x8 a0 = *(const f16x8*)(Ap + ks);
        f16x8 a1 = *(const f16x8*)(Ap + 16 * 256 + ks);
        f16x8 b0 = *(const f16x8*)(Bp + ks);
        f16x8 b1 = *(const f16x8*)(Bp + 16 * 256 + ks);
        f16x8 b2 = *(const f16x8*)(Bp + 32 * 256 + ks);
        f16x8 b3 = *(const f16x8*)(Bp + 48 * 256 + ks);
        acc[0][0] = __builtin_amdgcn_mfma_f32_16x16x32_f16(a0, b0, acc[0][0], 0, 0, 0);
        acc[0][1] = __builtin_amdgcn_mfma_f32_16x16x32_f16(a0, b1, acc[0][1], 0, 0, 0);
        acc[0][2] = __builtin_amdgcn_mfma_f32_16x16x32_f16(a0, b2, acc[0][2], 0, 0, 0);
        acc[0][3] = __builtin_amdgcn_mfma_f32_16x16x32_f16(a0, b3, acc[0][3], 0, 0, 0);
        acc[1][0] = __builtin_amdgcn_mfma_f32_16x16x32_f16(a1, b0, acc[1][0], 0, 0, 0);
        acc[1][1] = __builtin_amdgcn_mfma_f32_16x16x32_f16(a1, b1, acc[1][1], 0, 0, 0);
        acc[1][2] = __builtin_amdgcn_mfma_f32_16x16x32_f16(a1, b2, acc[1][2], 0, 0, 0);
        acc[1][3] = __builtin_amdgcn_mfma_f32_16x16x32_f16(a1, b3, acc[1][3], 0, 0, 0);
    }
    if (whT) {
#pragma unroll
        for (int mt = 0; mt < 2; mt++)
#pragma unroll
            for (int nt = 0; nt < 4; nt++) {
                f16x4 v;
#pragma unroll
                for (int reg = 0; reg < 4; reg++) v[reg] = (f16)acc[mt][nt][reg];
                *(f16x4*)(whT + (size_t)(n0 + nt * 16 + il) * ROWS + m0 + mt * 16 + q * 4) = v;
            }
    } else {
#pragma unroll
        for (int nt = 0; nt < 4; nt++) {
            float bv = bias[n0 + nt * 16 + il];
#pragma unroll
            for (int mt = 0; mt < 2; mt++)
#pragma unroll
                for (int reg = 0; reg < 4; reg++)
                    outF[(size_t)(m0 + mt * 16 + q * 4 + reg) * 256 + n0 + nt * 16 + il] =
                        acc[mt][nt][reg] + bv;
        }
    }
}

// ---------------------------------------------------------------- a_sT/a_dT = h16 . us/ud  (per head)
__global__ __launch_bounds__(256) void edge_from_h(
    const f16* __restrict__ h16, const float* __restrict__ us,
    const float* __restrict__ ud, float* __restrict__ a_sT, float* __restrict__ a_dT) {
    __shared__ float su[4][256], sd[4][256];
    int t = threadIdx.x;
#pragma unroll
    for (int i = 0; i < 4; i++) { su[i][t] = us[i * 256 + t]; sd[i][t] = ud[i * 256 + t]; }
    __syncthreads();
    int row = blockIdx.x * 256 + t;
    const f16* hp = h16 + (size_t)row * 256;
    float aS[4] = {0.f, 0.f, 0.f, 0.f}, aD[4] = {0.f, 0.f, 0.f, 0.f};
    for (int kk = 0; kk < 32; kk++) {
        f16x8 hv = *(const f16x8*)(hp + kk * 8);
#pragma unroll
        for (int j = 0; j < 8; j++) {
            float hf = (float)hv[j];
            int k = kk * 8 + j;
#pragma unroll
            for (int h = 0; h < 4; h++) {
                aS[h] = fmaf(hf, su[h][k], aS[h]);
                aD[h] = fmaf(hf, sd[h][k], aD[h]);
            }
        }
    }
#pragma unroll
    for (int h = 0; h < 4; h++) {
        a_sT[(size_t)h * ROWS + row] = aS[h];
        a_dT[(size_t)h * ROWS + row] = aD[h];
    }
}

// ---------------------------------------------------------------- per (b,h) max of a_s
__global__ __launch_bounds__(256) void reduce_max(const float* __restrict__ a_sT,
                                                  float* __restrict__ M) {
    int blk = blockIdx.x;           // b*4 + h
    int b = blk >> 2, h = blk & 3;
    const float* p = a_sT + (size_t)h * ROWS + b * NAGENT;
    int t = threadIdx.x;
    float m = fmaxf(fmaxf(p[t], p[t + 256]), fmaxf(p[t + 512], p[t + 768]));
#pragma unroll
    for (int off = 32; off > 0; off >>= 1) m = fmaxf(m, __shfl_down(m, off));
    __shared__ float red[4];
    if ((t & 63) == 0) red[t >> 6] = m;
    __syncthreads();
    if (t == 0) M[blk] = fmaxf(fmaxf(red[0], red[1]), fmaxf(red[2], red[3]));
}

// ---------------------------------------------------------------- fused GAT attention (f16 MFMA, ones-column row sums)
__global__ __launch_bounds__(256, 4) void gat_attn(
    const f16* __restrict__ whT, const float* __restrict__ a_sT,
    const float* __restrict__ a_dT, const unsigned int* __restrict__ mask,
    const float* __restrict__ M, const float* __restrict__ gat_b,
    f16* __restrict__ h16out) {
    int t = threadIdx.x;
    int blk = blockIdx.x;
    int b = blk >> 6;
    int i0 = (blk & 63) << 4;
    int base = b << 10;
    int h = t >> 6, lane = t & 63;
    int il = lane & 15, q = lane >> 4;
    int ig = i0 + il;

    float adv = a_dT[(size_t)h * ROWS + base + ig];
    float mz = M[b * 4 + h] + adv;
    float m_i = fmaxf(mz, 0.2f * mz);       // leaky(maxj a_s + a_d_i) >= row max
    float nm = -m_i * LOG2E;

    f32x4 acc0 = {0.f,0.f,0.f,0.f}, acc1 = acc0, acc2 = acc0, acc3 = acc0, accS = acc0;
    f16x8 ones;
#pragma unroll
    for (int j = 0; j < 8; j++) ones[j] = (f16)1.f;

    const f16*   wp  = whT + (size_t)(h * 64 + il) * ROWS + base + q * 8;
    const float* asp = a_sT + (size_t)h * ROWS + base + q * 8;
    const unsigned char* mrow =
        (const unsigned char*)(mask + (((size_t)(base + ig)) << 5)) + q;

    for (int c = 0; c < 32; ++c) {
        int j0 = c * 32;
        f16x8 b0 = *(const f16x8*)(wp + j0);
        f16x8 b1 = *(const f16x8*)(wp + (size_t)16 * ROWS + j0);
        f16x8 b2 = *(const f16x8*)(wp + (size_t)32 * ROWS + j0);
        f16x8 b3 = *(const f16x8*)(wp + (size_t)48 * ROWS + j0);
        float4 as0 = *(const float4*)(asp + j0);
        float4 as1 = *(const float4*)(asp + j0 + 4);
        unsigned int mb = mrow[c * 4];
        float asv[8] = {as0.x, as0.y, as0.z, as0.w, as1.x, as1.y, as1.z, as1.w};
        f16x8 afr;
#pragma unroll
        for (int jj = 0; jj < 8; ++jj) {
            float z = asv[jj] + adv;
            float sc = fmaxf(z, 0.2f * z);
            float e = exp2f(fmaf(sc, LOG2E, nm));
            float p = ((mb >> jj) & 1u) ? e : 0.f;
            afr[jj] = (f16)p;
        }
        acc0 = __builtin_amdgcn_mfma_f32_16x16x32_f16(afr, b0, acc0, 0, 0, 0);
        acc1 = __builtin_amdgcn_mfma_f32_16x16x32_f16(afr, b1, acc1, 0, 0, 0);
        acc2 = __builtin_amdgcn_mfma_f32_16x16x32_f16(afr, b2, acc2, 0, 0, 0);
        acc3 = __builtin_amdgcn_mfma_f32_16x16x32_f16(afr, b3, acc3, 0, 0, 0);
        accS = __builtin_amdgcn_mfma_f32_16x16x32_f16(afr, ones, accS, 0, 0, 0);
    }
    float b0v = gat_b[h * 64 + il];
    float b1v = gat_b[h * 64 + 16 + il];
    float b2v = gat_b[h * 64 + 32 + il];
    float b3v = gat_b[h * 64 + 48 + il];
#pragma unroll
    for (int reg = 0; reg < 4; ++reg) {
        float inv = 1.f / accS[reg];        // row sum for row q*4+reg (same across cols)
        size_t ro = (size_t)(base + i0 + q * 4 + reg) * DIM + h * 64 + il;
        h16out[ro +  0] = (f16)fmaxf(fmaf(acc0[reg], inv, b0v), 0.f);
        h16out[ro + 16] = (f16)fmaxf(fmaf(acc1[reg], inv, b1v), 0.f);
        h16out[ro + 32] = (f16)fmaxf(fmaf(acc2[reg], inv, b2v), 0.f);
        h16out[ro + 48] = (f16)fmaxf(fmaf(acc3[reg], inv, b3v), 0.f);
    }
}

// ---------------------------------------------------------------- mask zeros
__global__ void zero_mask(float* __restrict__ p) {
    p[blockIdx.x * 256 + threadIdx.x] = 0.f;
}

// ---------------------------------------------------------------- launch
extern "C" void kernel_launch(void* const* d_in, const int* in_sizes, int n_in,
                              void* d_out, int out_size, void* d_ws, size_t ws_size,
                              hipStream_t stream) {
    const float* ego       = (const float*)d_in[0];
    const float* nbr       = (const float*)d_in[1];
    const float* node_w    = (const float*)d_in[2];
    const float* node_b    = (const float*)d_in[3];
    const float* node_g    = (const float*)d_in[4];
    const float* node_beta = (const float*)d_in[5];
    const float* ego_w     = (const float*)d_in[6];
    const float* ego_b     = (const float*)d_in[7];
    const float* ego_g     = (const float*)d_in[8];
    const float* ego_beta  = (const float*)d_in[9];
    const float* gat_w     = (const float*)d_in[10];
    const float* gat_asrc  = (const float*)d_in[11];
    const float* gat_adst  = (const float*)d_in[12];
    const float* gat_bias  = (const float*)d_in[13];
    const float* proj_w    = (const float*)d_in[14];
    const float* proj_b    = (const float*)d_in[15];

    float* out = (float*)d_out;
    float* ws  = (float*)d_ws;
    float* x    = ws + O_X;
    float* px   = ws + O_PX;
    float* py   = ws + O_PY;
    f16*   h16  = (f16*)(ws + O_H16);
    float* asT  = ws + O_AS;
    float* adT  = ws + O_AD;
    float* Mmax = ws + O_M;
    float* us   = ws + O_US;
    float* ud   = ws + O_UD;
    f16*   WT   = (f16*)(ws + O_WT);
    unsigned int* adj = (unsigned int*)(ws + O_ADJ);
    f16*   whT  = (f16*)d_out;      // 8 MB scratch in d_out; proj overwrites last

    build_x<<<64, 256, 0, stream>>>(ego, nbr, x, px, py);
    adj_build<<<1024, 256, 0, stream>>>(px, py, adj);
    prep_usud<<<8, 256, 0, stream>>>(gat_w, gat_asrc, gat_adst, us, ud);
    transpose_w<<<48, 256, 0, stream>>>(gat_w, proj_w, WT);
    node_embed<<<4096, 256, 0, stream>>>(x, node_w, node_b, node_g, node_beta,
                                         ego_w, ego_b, ego_g, ego_beta, h16);
    for (int l = 0; l < 2; l++) {
        gemm_f16<<<512, 256, 0, stream>>>(h16, WT + (size_t)l * 65536, whT, nullptr, nullptr);
        edge_from_h<<<64, 256, 0, stream>>>(h16, us + l * 1024, ud + l * 1024, asT, adT);
        reduce_max<<<64, 256, 0, stream>>>(asT, Mmax);
        gat_attn<<<1024, 256, 0, stream>>>(whT, asT, adT, adj, Mmax,
                                           gat_bias + l * 256, h16);
    }
    gemm_f16<<<512, 256, 0, stream>>>(h16, WT + (size_t)2 * 65536, nullptr, out, proj_b);
    zero_mask<<<64, 256, 0, stream>>>(out + (size_t)ROWS * DIM);
}